// Round 1
// baseline (212.000 us; speedup 1.0000x reference)
//
#include <hip/hip_runtime.h>

#define TT 8192
#define CIN 512
#define COUT 512
#define NB 8
#define KTOT 1536   // 3 * CIN

typedef __attribute__((ext_vector_type(4))) float f32x4;
typedef __attribute__((ext_vector_type(8))) short bf16x8;
typedef __attribute__((ext_vector_type(8))) unsigned short u16x8;

__device__ inline unsigned short f2bf(float f) {
  union { float f; unsigned int u; } v; v.f = f;
  unsigned int u = v.u;
  unsigned int r = (u + 0x7FFFu + ((u >> 16) & 1u)) >> 16;  // RNE
  return (unsigned short)r;
}

// Build A = [W0 | W1 | W2] (COUT x KTOT) in bf16. grid (1024, 3), block 256
__global__ void k_convert_w(const float* __restrict__ W0, const float* __restrict__ W1,
                            const float* __restrict__ W2, unsigned short* __restrict__ Wb) {
  int i = blockIdx.x * 256 + threadIdx.x;
  if (i >= COUT * CIN) return;
  const float* Ws = blockIdx.y == 0 ? W0 : (blockIdx.y == 1 ? W1 : W2);
  int o = i >> 9, c = i & 511;
  Wb[(size_t)o * KTOT + blockIdx.y * CIN + c] = f2bf(Ws[i]);
}

// x (B, C, T) fp32 -> xbT (T, C) bf16 per batch. grid (T/64, C/64, nb), block 256
__global__ void k_transpose(const float* __restrict__ x, unsigned short* __restrict__ xbT,
                            int b_base) {
  int b = b_base + blockIdx.z;
  const float* xb = x + (size_t)b * CIN * TT;
  unsigned short* xo = xbT + (size_t)blockIdx.z * TT * CIN;
  __shared__ float tile[64][65];
  int t0 = blockIdx.x * 64, c0 = blockIdx.y * 64;
  int tid = threadIdx.x;
#pragma unroll
  for (int it = 0; it < 16; ++it) {
    int L = it * 256 + tid;
    int c = L >> 6, t = L & 63;
    tile[c][t] = xb[(size_t)(c0 + c) * TT + (t0 + t)];
  }
  __syncthreads();
#pragma unroll
  for (int it = 0; it < 16; ++it) {
    int L = it * 256 + tid;
    int t = L >> 6, c = L & 63;
    xo[(size_t)(t0 + t) * CIN + (c0 + c)] = f2bf(tile[c][t]);
  }
}

// Fused gather-GEMM: out[b, m, t] = sum_s sum_c Ws[m,c] * xbT[idx_s(t), c] + bias[m]
// A = Wb (COUT x KTOT), B-tile rows gathered via per-row pointers.
// grid (COUT/128, TT/128, nb), block 256 (4 waves, 2x2)
__global__ __launch_bounds__(256) void k_gemm(
    const unsigned short* __restrict__ Wb, const unsigned short* __restrict__ xbT,
    const float* __restrict__ d, const float* __restrict__ bias,
    float* __restrict__ out, int b_base) {
  __shared__ __align__(16) unsigned short As[128 * 32];
  __shared__ __align__(16) unsigned short Bs[128 * 32];
  int b = b_base + blockIdx.z;
  const unsigned short* xb = xbT + (size_t)blockIdx.z * TT * CIN;
  int row0 = blockIdx.x * 128;
  int t0 = blockIdx.y * 128;
  int tid = threadIdx.x;
  int lane = tid & 63, wid = tid >> 6;
  int wr = wid >> 1, wc = wid & 1;
  int l15 = lane & 15, kg = lane >> 4;

  // staging assignment: this thread covers rows rs and rs+64, 16B chunk cch
  int rs = tid >> 2, cch = tid & 3;

  const unsigned short* aw[2];
  const unsigned short* bw[2][3];
  int sOff[2];
#pragma unroll
  for (int h = 0; h < 2; ++h) {
    int r = rs + h * 64;
    aw[h] = Wb + (size_t)(row0 + r) * KTOT + cch * 8;
    int t = t0 + r;
    float dv = d[(size_t)b * TT + t];
    int dil = (int)dv; if (dil < 1) dil = 1;
    int p = t - dil; if (p < 0) p = -p; p &= (TT - 1);
    int f0 = t + dil;
    int f = (f0 >= TT) ? (TT - 1 - (f0 & (TT - 1))) : f0;
    bw[h][0] = xb + (size_t)p * CIN + cch * 8;
    bw[h][1] = xb + (size_t)t * CIN + cch * 8;
    bw[h][2] = xb + (size_t)f * CIN + cch * 8;
    int sc = cch ^ ((r >> 1) & 3);
    sOff[h] = r * 32 + sc * 8;   // swizzled LDS ushort offset
  }

  // fragment read offsets (fixed per thread), same swizzle
  int aoff[4], boff[4];
#pragma unroll
  for (int mi = 0; mi < 4; ++mi) {
    int r = wr * 64 + mi * 16 + l15;
    aoff[mi] = r * 32 + (kg ^ ((r >> 1) & 3)) * 8;
  }
#pragma unroll
  for (int ni = 0; ni < 4; ++ni) {
    int r = wc * 64 + ni * 16 + l15;
    boff[ni] = r * 32 + (kg ^ ((r >> 1) & 3)) * 8;
  }

  f32x4 acc[4][4] = {};

#pragma unroll
  for (int s = 0; s < 3; ++s) {
    for (int kt = 0; kt < 16; ++kt) {
      int koff = kt * 32;  // ushorts within segment
#pragma unroll
      for (int h = 0; h < 2; ++h) {
        u16x8 va = *(const u16x8*)(aw[h] + s * CIN + koff);
        u16x8 vb = *(const u16x8*)(bw[h][s] + koff);
        *(u16x8*)(&As[sOff[h]]) = va;
        *(u16x8*)(&Bs[sOff[h]]) = vb;
      }
      __syncthreads();
      bf16x8 af[4], bf[4];
#pragma unroll
      for (int mi = 0; mi < 4; ++mi) af[mi] = *(const bf16x8*)(&As[aoff[mi]]);
#pragma unroll
      for (int ni = 0; ni < 4; ++ni) bf[ni] = *(const bf16x8*)(&Bs[boff[ni]]);
#pragma unroll
      for (int mi = 0; mi < 4; ++mi)
#pragma unroll
        for (int ni = 0; ni < 4; ++ni)
          acc[mi][ni] = __builtin_amdgcn_mfma_f32_16x16x32_bf16(af[mi], bf[ni],
                                                                acc[mi][ni], 0, 0, 0);
      __syncthreads();
    }
  }

  float* ob = out + (size_t)b * COUT * TT;
#pragma unroll
  for (int mi = 0; mi < 4; ++mi) {
    int m0 = row0 + wr * 64 + mi * 16 + kg * 4;
#pragma unroll
    for (int ni = 0; ni < 4; ++ni) {
      int t = t0 + wc * 64 + ni * 16 + l15;
#pragma unroll
      for (int j = 0; j < 4; ++j) {
        ob[(size_t)(m0 + j) * TT + t] = acc[mi][ni][j] + bias[m0 + j];
      }
    }
  }
}

// ws-free fallback (only if ws is tiny). grid (T/256, COUT, B)
__global__ void k_naive(const float* __restrict__ x, const float* __restrict__ d,
                        const float* __restrict__ W0, const float* __restrict__ b0,
                        const float* __restrict__ W1, const float* __restrict__ W2,
                        float* __restrict__ out) {
  int t = blockIdx.x * 256 + threadIdx.x;
  int o = blockIdx.y, b = blockIdx.z;
  const float* xb = x + (size_t)b * CIN * TT;
  float dv = d[(size_t)b * TT + t];
  int dil = (int)dv; if (dil < 1) dil = 1;
  int p = t - dil; if (p < 0) p = -p; p &= (TT - 1);
  int f0 = t + dil;
  int f = (f0 >= TT) ? (TT - 1 - (f0 & (TT - 1))) : f0;
  float a0 = 0.f, a1 = 0.f, a2 = 0.f;
  for (int c = 0; c < CIN; ++c) {
    const float* xc = xb + (size_t)c * TT;
    a0 += W0[o * CIN + c] * xc[p];
    a1 += W1[o * CIN + c] * xc[t];
    a2 += W2[o * CIN + c] * xc[f];
  }
  out[((size_t)b * COUT + o) * TT + t] = a0 + a1 + a2 + b0[o];
}

extern "C" void kernel_launch(void* const* d_in, const int* in_sizes, int n_in,
                              void* d_out, int out_size, void* d_ws, size_t ws_size,
                              hipStream_t stream) {
  const float* x  = (const float*)d_in[0];
  const float* d  = (const float*)d_in[1];
  const float* W0 = (const float*)d_in[2];
  const float* b0 = (const float*)d_in[3];
  const float* W1 = (const float*)d_in[4];
  const float* W2 = (const float*)d_in[5];
  float* out = (float*)d_out;

  char* ws = (char*)d_ws;
  unsigned short* Wb  = (unsigned short*)ws;                       // 1.5 MiB
  unsigned short* xbT = (unsigned short*)(ws + (2u << 20));        // 8 MiB per batch
  const size_t SZ_XBT1 = (size_t)TT * CIN * 2;
  const size_t NEED_FULL = (size_t)(2u << 20) + (size_t)NB * SZ_XBT1;  // ~66 MiB
  const size_t NEED_MIN  = (size_t)(2u << 20) + SZ_XBT1;               // ~10 MiB

  if (ws_size >= NEED_MIN) {
    k_convert_w<<<dim3(1024, 3), 256, 0, stream>>>(W0, W1, W2, Wb);
    if (ws_size >= NEED_FULL) {
      k_transpose<<<dim3(TT / 64, CIN / 64, NB), 256, 0, stream>>>(x, xbT, 0);
      k_gemm<<<dim3(COUT / 128, TT / 128, NB), 256, 0, stream>>>(Wb, xbT, d, b0, out, 0);
    } else {
      for (int b = 0; b < NB; ++b) {
        k_transpose<<<dim3(TT / 64, CIN / 64, 1), 256, 0, stream>>>(x, xbT, b);
        k_gemm<<<dim3(COUT / 128, TT / 128, 1), 256, 0, stream>>>(Wb, xbT, d, b0, out, b);
      }
    }
  } else {
    k_naive<<<dim3(TT / 256, COUT, NB), 256, 0, stream>>>(x, d, W0, b0, W1, W2, out);
  }
}

// Round 2
// 202.473 us; speedup vs baseline: 1.0471x; 1.0471x over previous
//
#include <hip/hip_runtime.h>

#define TT 8192
#define CIN 512
#define COUT 512
#define NB 8
#define KTOT 1536   // 3 * CIN

typedef __attribute__((ext_vector_type(4))) float f32x4;
typedef __attribute__((ext_vector_type(8))) short bf16x8;
typedef __attribute__((ext_vector_type(8))) unsigned short u16x8;

// async global->LDS, 16B per lane; LDS dest is wave-uniform base + lane*16
#define GLD16(g, l) __builtin_amdgcn_global_load_lds(                      \
    (const __attribute__((address_space(1))) void*)(g),                    \
    (__attribute__((address_space(3))) void*)(l), 16, 0, 0)

__device__ inline unsigned short f2bf(float f) {
  union { float f; unsigned int u; } v; v.f = f;
  unsigned int u = v.u;
  unsigned int r = (u + 0x7FFFu + ((u >> 16) & 1u)) >> 16;  // RNE
  return (unsigned short)r;
}

// Build A = [W0 | W1 | W2] (COUT x KTOT) in bf16. grid (1024, 3), block 256
__global__ void k_convert_w(const float* __restrict__ W0, const float* __restrict__ W1,
                            const float* __restrict__ W2, unsigned short* __restrict__ Wb) {
  int i = blockIdx.x * 256 + threadIdx.x;
  if (i >= COUT * CIN) return;
  const float* Ws = blockIdx.y == 0 ? W0 : (blockIdx.y == 1 ? W1 : W2);
  int o = i >> 9, c = i & 511;
  Wb[(size_t)o * KTOT + blockIdx.y * CIN + c] = f2bf(Ws[i]);
}

// x (B, C, T) fp32 -> xbT (T, C) bf16 per batch. grid (T/64, C/64, nb), block 256
__global__ void k_transpose(const float* __restrict__ x, unsigned short* __restrict__ xbT,
                            int b_base) {
  int b = b_base + blockIdx.z;
  const float* xb = x + (size_t)b * CIN * TT;
  unsigned short* xo = xbT + (size_t)blockIdx.z * TT * CIN;
  __shared__ float tile[64][65];
  int t0 = blockIdx.x * 64, c0 = blockIdx.y * 64;
  int tid = threadIdx.x;
#pragma unroll
  for (int it = 0; it < 16; ++it) {
    int L = it * 256 + tid;
    int c = L >> 6, t = L & 63;
    tile[c][t] = xb[(size_t)(c0 + c) * TT + (t0 + t)];
  }
  __syncthreads();
#pragma unroll
  for (int it = 0; it < 16; ++it) {
    int L = it * 256 + tid;
    int t = L >> 6, c = L & 63;
    xo[(size_t)(t0 + t) * CIN + (c0 + c)] = f2bf(tile[c][t]);
  }
}

// Fused gather-GEMM: out[b, m, t] = sum_s sum_c Ws[m,c] * xbT[idx_s(t), c] + bias[m]
// A = Wb (COUT x KTOT). B-tile rows gathered via per-lane global addresses into
// global_load_lds (linear LDS dest; XOR chunk swizzle applied on the SOURCE).
// grid (COUT/128, TT/128, nb), block 256 (4 waves, 2x2)
__global__ __launch_bounds__(256) void k_gemm(
    const unsigned short* __restrict__ Wb, const unsigned short* __restrict__ xbT,
    const float* __restrict__ d, const float* __restrict__ bias,
    float* __restrict__ out, int b_base) {
  __shared__ __align__(16) unsigned short As[128 * 32];
  __shared__ __align__(16) unsigned short Bs[128 * 32];
  int b = b_base + blockIdx.z;
  const unsigned short* xb = xbT + (size_t)blockIdx.z * TT * CIN;
  int row0 = blockIdx.x * 128;
  int t0 = blockIdx.y * 128;
  int tid = threadIdx.x;
  int lane = tid & 63, wid = tid >> 6;
  int wr = wid >> 1, wc = wid & 1;
  int l15 = lane & 15, kg = lane >> 4;

  // staging: thread covers rows rs and rs+64, 16B chunk cch; LDS write is
  // linear (HW: wave base + lane*16), so the swizzle goes on the SOURCE chunk.
  int rs = tid >> 2, cch = tid & 3;

  const unsigned short* aw[2];
  const unsigned short* bw[2][3];
#pragma unroll
  for (int h = 0; h < 2; ++h) {
    int r = rs + h * 64;
    int cs = cch ^ ((r >> 1) & 3);  // swizzled source chunk (involution)
    aw[h] = Wb + (size_t)(row0 + r) * KTOT + cs * 8;
    int t = t0 + r;
    float dv = d[(size_t)b * TT + t];
    int dil = (int)dv; if (dil < 1) dil = 1;
    int p = t - dil; if (p < 0) p = -p; p &= (TT - 1);
    int f0 = t + dil;
    int f = (f0 >= TT) ? (TT - 1 - (f0 & (TT - 1))) : f0;
    bw[h][0] = xb + (size_t)p * CIN + cs * 8;
    bw[h][1] = xb + (size_t)t * CIN + cs * 8;
    bw[h][2] = xb + (size_t)f * CIN + cs * 8;
  }
  // wave-uniform LDS destinations (ushort units): h*2048 + wave*512
  unsigned short* aDst[2];
  unsigned short* bDst[2];
#pragma unroll
  for (int h = 0; h < 2; ++h) {
    aDst[h] = As + h * 2048 + wid * 512;
    bDst[h] = Bs + h * 2048 + wid * 512;
  }

  // fragment read offsets (fixed per thread), swizzled chunk
  int aoff[4], boff[4];
#pragma unroll
  for (int mi = 0; mi < 4; ++mi) {
    int r = wr * 64 + mi * 16 + l15;
    aoff[mi] = r * 32 + (kg ^ ((r >> 1) & 3)) * 8;
  }
#pragma unroll
  for (int ni = 0; ni < 4; ++ni) {
    int r = wc * 64 + ni * 16 + l15;
    boff[ni] = r * 32 + (kg ^ ((r >> 1) & 3)) * 8;
  }

  f32x4 acc[4][4] = {};

#pragma unroll
  for (int s = 0; s < 3; ++s) {
    for (int kt = 0; kt < 16; ++kt) {
      int koff = kt * 32;  // ushorts within segment
#pragma unroll
      for (int h = 0; h < 2; ++h) {
        GLD16(aw[h] + s * CIN + koff, aDst[h]);
        GLD16(bw[h][s] + koff, bDst[h]);
      }
      __syncthreads();  // drains vmcnt(0): staged data visible
      bf16x8 af[4], bf[4];
#pragma unroll
      for (int mi = 0; mi < 4; ++mi) af[mi] = *(const bf16x8*)(&As[aoff[mi]]);
#pragma unroll
      for (int ni = 0; ni < 4; ++ni) bf[ni] = *(const bf16x8*)(&Bs[boff[ni]]);
#pragma unroll
      for (int mi = 0; mi < 4; ++mi)
#pragma unroll
        for (int ni = 0; ni < 4; ++ni)
          acc[mi][ni] = __builtin_amdgcn_mfma_f32_16x16x32_bf16(af[mi], bf[ni],
                                                                acc[mi][ni], 0, 0, 0);
      __syncthreads();
    }
  }

  float* ob = out + (size_t)b * COUT * TT;
#pragma unroll
  for (int mi = 0; mi < 4; ++mi) {
    int m0 = row0 + wr * 64 + mi * 16 + kg * 4;
#pragma unroll
    for (int ni = 0; ni < 4; ++ni) {
      int t = t0 + wc * 64 + ni * 16 + l15;
#pragma unroll
      for (int j = 0; j < 4; ++j) {
        ob[(size_t)(m0 + j) * TT + t] = acc[mi][ni][j] + bias[m0 + j];
      }
    }
  }
}

// ws-free fallback (only if ws is tiny). grid (T/256, COUT, B)
__global__ void k_naive(const float* __restrict__ x, const float* __restrict__ d,
                        const float* __restrict__ W0, const float* __restrict__ b0,
                        const float* __restrict__ W1, const float* __restrict__ W2,
                        float* __restrict__ out) {
  int t = blockIdx.x * 256 + threadIdx.x;
  int o = blockIdx.y, b = blockIdx.z;
  const float* xb = x + (size_t)b * CIN * TT;
  float dv = d[(size_t)b * TT + t];
  int dil = (int)dv; if (dil < 1) dil = 1;
  int p = t - dil; if (p < 0) p = -p; p &= (TT - 1);
  int f0 = t + dil;
  int f = (f0 >= TT) ? (TT - 1 - (f0 & (TT - 1))) : f0;
  float a0 = 0.f, a1 = 0.f, a2 = 0.f;
  for (int c = 0; c < CIN; ++c) {
    const float* xc = xb + (size_t)c * TT;
    a0 += W0[o * CIN + c] * xc[p];
    a1 += W1[o * CIN + c] * xc[t];
    a2 += W2[o * CIN + c] * xc[f];
  }
  out[((size_t)b * COUT + o) * TT + t] = a0 + a1 + a2 + b0[o];
}

extern "C" void kernel_launch(void* const* d_in, const int* in_sizes, int n_in,
                              void* d_out, int out_size, void* d_ws, size_t ws_size,
                              hipStream_t stream) {
  const float* x  = (const float*)d_in[0];
  const float* d  = (const float*)d_in[1];
  const float* W0 = (const float*)d_in[2];
  const float* b0 = (const float*)d_in[3];
  const float* W1 = (const float*)d_in[4];
  const float* W2 = (const float*)d_in[5];
  float* out = (float*)d_out;

  char* ws = (char*)d_ws;
  unsigned short* Wb  = (unsigned short*)ws;                       // 1.5 MiB
  unsigned short* xbT = (unsigned short*)(ws + (2u << 20));        // 8 MiB per batch
  const size_t SZ_XBT1 = (size_t)TT * CIN * 2;
  const size_t NEED_FULL = (size_t)(2u << 20) + (size_t)NB * SZ_XBT1;  // ~66 MiB
  const size_t NEED_MIN  = (size_t)(2u << 20) + SZ_XBT1;               // ~10 MiB

  if (ws_size >= NEED_MIN) {
    k_convert_w<<<dim3(1024, 3), 256, 0, stream>>>(W0, W1, W2, Wb);
    if (ws_size >= NEED_FULL) {
      k_transpose<<<dim3(TT / 64, CIN / 64, NB), 256, 0, stream>>>(x, xbT, 0);
      k_gemm<<<dim3(COUT / 128, TT / 128, NB), 256, 0, stream>>>(Wb, xbT, d, b0, out, 0);
    } else {
      for (int b = 0; b < NB; ++b) {
        k_transpose<<<dim3(TT / 64, CIN / 64, 1), 256, 0, stream>>>(x, xbT, b);
        k_gemm<<<dim3(COUT / 128, TT / 128, 1), 256, 0, stream>>>(Wb, xbT, d, b0, out, b);
      }
    }
  } else {
    k_naive<<<dim3(TT / 256, COUT, NB), 256, 0, stream>>>(x, d, W0, b0, W1, W2, out);
  }
}

// Round 3
// 153.143 us; speedup vs baseline: 1.3843x; 1.3221x over previous
//
#include <hip/hip_runtime.h>

#define TT 8192
#define CIN 512
#define COUT 512
#define NB 8
#define KTOT 1536   // 3 * CIN
#define NT 24       // K tiles of 64

typedef __attribute__((ext_vector_type(4))) float f32x4;
typedef __attribute__((ext_vector_type(8))) short bf16x8;
typedef __attribute__((ext_vector_type(8))) unsigned short u16x8;

#define GLD16(g, l) __builtin_amdgcn_global_load_lds(                      \
    (const __attribute__((address_space(1))) void*)(g),                    \
    (__attribute__((address_space(3))) void*)(l), 16, 0, 0)

#define CFENCE() asm volatile("" ::: "memory")
#define SCHED() __builtin_amdgcn_sched_barrier(0)
#define SBAR() do { CFENCE(); SCHED(); __builtin_amdgcn_s_barrier(); SCHED(); CFENCE(); } while (0)
#define VMCNT4() asm volatile("s_waitcnt vmcnt(4)" ::: "memory")
#define VMCNT0() asm volatile("s_waitcnt vmcnt(0)" ::: "memory")
#define LGKM0() asm volatile("s_waitcnt lgkmcnt(0)" ::: "memory")
#define MFMA(a_, b_, c_) __builtin_amdgcn_mfma_f32_16x16x32_bf16((a_), (b_), (c_), 0, 0, 0)

__device__ inline unsigned short f2bf(float f) {
  union { float f; unsigned int u; } v; v.f = f;
  unsigned int u = v.u;
  unsigned int r = (u + 0x7FFFu + ((u >> 16) & 1u)) >> 16;  // RNE
  return (unsigned short)r;
}

__global__ void k_convert_w(const float* __restrict__ W0, const float* __restrict__ W1,
                            const float* __restrict__ W2, unsigned short* __restrict__ Wb) {
  int i = blockIdx.x * 256 + threadIdx.x;
  if (i >= COUT * CIN) return;
  const float* Ws = blockIdx.y == 0 ? W0 : (blockIdx.y == 1 ? W1 : W2);
  int o = i >> 9, c = i & 511;
  Wb[(size_t)o * KTOT + blockIdx.y * CIN + c] = f2bf(Ws[i]);
}

// x (B, C, T) fp32 -> xbT (T, C) bf16 per batch. grid (T/64, C/64, nb), block 256
__global__ void k_transpose(const float* __restrict__ x, unsigned short* __restrict__ xbT,
                            int b_base) {
  int b = b_base + blockIdx.z;
  const float* xb = x + (size_t)b * CIN * TT;
  unsigned short* xo = xbT + (size_t)blockIdx.z * TT * CIN;
  __shared__ float tile[64][65];
  int t0 = blockIdx.x * 64, c0 = blockIdx.y * 64;
  int tid = threadIdx.x;
#pragma unroll
  for (int it = 0; it < 16; ++it) {
    int L = it * 256 + tid;
    int c = L >> 6, t = L & 63;
    tile[c][t] = xb[(size_t)(c0 + c) * TT + (t0 + t)];
  }
  __syncthreads();
#pragma unroll
  for (int it = 0; it < 16; ++it) {
    int L = it * 256 + tid;
    int t = L >> 6, c = L & 63;
    xo[(size_t)(t0 + t) * CIN + (c0 + c)] = f2bf(tile[c][t]);
  }
}

// ---------------- 256x256 8-phase fused gather-GEMM ----------------
// grid (TT/256, COUT/256, NB), block 512 (8 waves, 2M x 4N)
__global__ __launch_bounds__(512) void k_gemm256(
    const unsigned short* __restrict__ Wb, const unsigned short* __restrict__ xbT,
    const float* __restrict__ d, const float* __restrict__ bias,
    float* __restrict__ out) {
  __shared__ __align__(16) unsigned short As[2][256 * 64];
  __shared__ __align__(16) unsigned short Bs[2][256 * 64];
  const int b = blockIdx.z;
  const unsigned short* xb = xbT + (size_t)b * TT * CIN;
  const int t0 = blockIdx.x * 256;
  const int row0 = blockIdx.y * 256;
  const int tid = threadIdx.x;
  const int lane = tid & 63, wid = tid >> 6;
  const int wr = wid >> 2, wc = wid & 3;
  const int l15 = lane & 15, kg = lane >> 4;

  // ---- staging sources: round j covers row r = j*64 + (tid>>3), chunk slot tid&7
  // source chunk = slot ^ ((r>>1)&7); with r = j*64+(tid>>3), (r>>1)&7 == (tid>>4)&7
  const int srow = tid >> 3;
  const int cSrc8 = (((tid & 7) ^ ((tid >> 4) & 7))) * 8;  // ushort offset of 16B chunk
  int aOff[4];        // Wb ushort offsets (row*KTOT + chunk), add tc*64
  int bOff[3][4];     // xbT ushort offsets per segment (row*CIN + chunk), add (tc&7)*64
#pragma unroll
  for (int j = 0; j < 4; ++j) {
    int r = j * 64 + srow;
    aOff[j] = (row0 + r) * KTOT + cSrc8;
    int t = t0 + r;
    float dv = d[(size_t)b * TT + t];
    int dil = (int)dv; if (dil < 1) dil = 1;
    int p = t - dil; if (p < 0) p = -p; p &= (TT - 1);
    int f0 = t + dil;
    int f = (f0 >= TT) ? (TT - 1 - (f0 & (TT - 1))) : f0;
    bOff[0][j] = p * CIN + cSrc8;
    bOff[1][j] = t * CIN + cSrc8;
    bOff[2][j] = f * CIN + cSrc8;
  }

  // ---- fragment read offsets (swizzled): row r, chunk (kh*4+kg) ^ ((r>>1)&7)
  // r = 16*base + l15 -> (r>>1)&7 == l15>>1; decompose XOR into base + dK for kh=1
  const int s7 = l15 >> 1;
  const int chunk0 = (kg ^ (s7 & 3)) + (s7 & 4);
  const int dK = (l15 & 8) ? -32 : 32;  // ushort delta for kh=1
  int aRd[2][4], bRd[2][2];
#pragma unroll
  for (int mh = 0; mh < 2; ++mh)
#pragma unroll
    for (int mi = 0; mi < 4; ++mi)
      aRd[mh][mi] = (wr * 128 + mh * 64 + mi * 16 + l15) * 64 + chunk0 * 8;
#pragma unroll
  for (int nh = 0; nh < 2; ++nh)
#pragma unroll
    for (int ni = 0; ni < 2; ++ni)
      bRd[nh][ni] = (wc * 64 + nh * 32 + ni * 16 + l15) * 64 + chunk0 * 8;

  // staging: 2 rounds per phase; dest ushort off = j*4096 + wid*512 (wave-linear)
#define STAGE_A2(tc_, buf_, jp_) do {                                         \
    _Pragma("unroll") for (int j = 2 * (jp_); j < 2 * (jp_) + 2; ++j)         \
      GLD16(Wb + aOff[j] + (tc_) * 64, &As[buf_][j * 4096 + wid * 512]);      \
  } while (0)
#define STAGE_B2(tc_, buf_, jp_) do {                                         \
    _Pragma("unroll") for (int j = 2 * (jp_); j < 2 * (jp_) + 2; ++j)         \
      GLD16(xb + bOff[(tc_) >> 3][j] + ((tc_) & 7) * 64,                      \
            &Bs[buf_][j * 4096 + wid * 512]);                                 \
  } while (0)

  // ---- prologue: A(0)->buf0, B(0)->buf0, A(1)->buf1; wait oldest 8, publish
  STAGE_A2(0, 0, 0); STAGE_A2(0, 0, 1);
  STAGE_B2(0, 0, 0); STAGE_B2(0, 0, 1);
  STAGE_A2(1, 1, 0); STAGE_A2(1, 1, 1);
  VMCNT4();
  SBAR();

  bf16x8 af0[4][2], af1[4][2], bfr[2][2];
  f32x4 acc[8][4] = {};

#pragma unroll
  for (int tc = 0; tc < NT; ++tc) {
    const int cur = tc & 1;
    // ---------- PH0: read A-half0 + B-half0; stage B(tc+1) r0-1; MFMA Q(0,0)
#pragma unroll
    for (int mi = 0; mi < 4; ++mi) {
      af0[mi][0] = *(const bf16x8*)&As[cur][aRd[0][mi]];
      af0[mi][1] = *(const bf16x8*)&As[cur][aRd[0][mi] + dK];
    }
#pragma unroll
    for (int ni = 0; ni < 2; ++ni) {
      bfr[ni][0] = *(const bf16x8*)&Bs[cur][bRd[0][ni]];
      bfr[ni][1] = *(const bf16x8*)&Bs[cur][bRd[0][ni] + dK];
    }
    if (tc + 1 < NT) STAGE_B2(tc + 1, cur ^ 1, 0);
    SBAR();
    LGKM0(); SCHED();
    __builtin_amdgcn_s_setprio(1);
#pragma unroll
    for (int mi = 0; mi < 4; ++mi)
#pragma unroll
      for (int ni = 0; ni < 2; ++ni) {
        acc[mi][ni] = MFMA(af0[mi][0], bfr[ni][0], acc[mi][ni]);
        acc[mi][ni] = MFMA(af0[mi][1], bfr[ni][1], acc[mi][ni]);
      }
    __builtin_amdgcn_s_setprio(0);
    SBAR();
    // ---------- PH1: read A-half1; stage B(tc+1) r2-3; MFMA Q(1,0)
#pragma unroll
    for (int mi = 0; mi < 4; ++mi) {
      af1[mi][0] = *(const bf16x8*)&As[cur][aRd[1][mi]];
      af1[mi][1] = *(const bf16x8*)&As[cur][aRd[1][mi] + dK];
    }
    if (tc + 1 < NT) STAGE_B2(tc + 1, cur ^ 1, 1);
    SBAR();
    LGKM0(); SCHED();
    __builtin_amdgcn_s_setprio(1);
#pragma unroll
    for (int mi = 0; mi < 4; ++mi)
#pragma unroll
      for (int ni = 0; ni < 2; ++ni) {
        acc[4 + mi][ni] = MFMA(af1[mi][0], bfr[ni][0], acc[4 + mi][ni]);
        acc[4 + mi][ni] = MFMA(af1[mi][1], bfr[ni][1], acc[4 + mi][ni]);
      }
    __builtin_amdgcn_s_setprio(0);
    SBAR();
    // ---------- PH2: read B-half1 (overwrite bfr); stage A(tc+2) r0-1; MFMA Q(0,1)
#pragma unroll
    for (int ni = 0; ni < 2; ++ni) {
      bfr[ni][0] = *(const bf16x8*)&Bs[cur][bRd[1][ni]];
      bfr[ni][1] = *(const bf16x8*)&Bs[cur][bRd[1][ni] + dK];
    }
    if (tc + 2 < NT) STAGE_A2(tc + 2, cur, 0);
    SBAR();
    LGKM0(); SCHED();
    __builtin_amdgcn_s_setprio(1);
#pragma unroll
    for (int mi = 0; mi < 4; ++mi)
#pragma unroll
      for (int ni = 0; ni < 2; ++ni) {
        acc[mi][2 + ni] = MFMA(af0[mi][0], bfr[ni][0], acc[mi][2 + ni]);
        acc[mi][2 + ni] = MFMA(af0[mi][1], bfr[ni][1], acc[mi][2 + ni]);
      }
    __builtin_amdgcn_s_setprio(0);
    SBAR();
    // ---------- PH3: stage A(tc+2) r2-3; MFMA Q(1,1); counted vmcnt; publish
    if (tc + 2 < NT) STAGE_A2(tc + 2, cur, 1);
    SBAR();
    SCHED();
    __builtin_amdgcn_s_setprio(1);
#pragma unroll
    for (int mi = 0; mi < 4; ++mi)
#pragma unroll
      for (int ni = 0; ni < 2; ++ni) {
        acc[4 + mi][2 + ni] = MFMA(af1[mi][0], bfr[ni][0], acc[4 + mi][2 + ni]);
        acc[4 + mi][2 + ni] = MFMA(af1[mi][1], bfr[ni][1], acc[4 + mi][2 + ni]);
      }
    __builtin_amdgcn_s_setprio(0);
    SCHED();
    if (tc + 2 < NT) { VMCNT4(); }        // keep A(tc+2) in flight
    else if (tc + 1 < NT) { VMCNT0(); }   // tail: drain for last tile
    SBAR();
  }

  // ---- epilogue: bias + fp32 store (coalesced over t within 16-lane groups)
  float* ob = out + (size_t)b * COUT * TT;
#pragma unroll
  for (int mh = 0; mh < 2; ++mh)
#pragma unroll
    for (int mi = 0; mi < 4; ++mi) {
      int m0 = row0 + wr * 128 + mh * 64 + mi * 16 + kg * 4;
#pragma unroll
      for (int nh = 0; nh < 2; ++nh)
#pragma unroll
        for (int ni = 0; ni < 2; ++ni) {
          int t = t0 + wc * 64 + nh * 32 + ni * 16 + l15;
          f32x4 v = acc[mh * 4 + mi][nh * 2 + ni];
#pragma unroll
          for (int j = 0; j < 4; ++j)
            ob[(size_t)(m0 + j) * TT + t] = v[j] + bias[m0 + j];
        }
    }
}

// ---------------- fallback 128x128 (small ws) ----------------
__global__ __launch_bounds__(256) void k_gemm(
    const unsigned short* __restrict__ Wb, const unsigned short* __restrict__ xbT,
    const float* __restrict__ d, const float* __restrict__ bias,
    float* __restrict__ out, int b_base) {
  __shared__ __align__(16) unsigned short As[128 * 32];
  __shared__ __align__(16) unsigned short Bs[128 * 32];
  int b = b_base + blockIdx.z;
  const unsigned short* xb = xbT + (size_t)blockIdx.z * TT * CIN;
  int row0 = blockIdx.x * 128;
  int t0 = blockIdx.y * 128;
  int tid = threadIdx.x;
  int lane = tid & 63, wid = tid >> 6;
  int wr = wid >> 1, wc = wid & 1;
  int l15 = lane & 15, kg = lane >> 4;
  int rs = tid >> 2, cch = tid & 3;

  const unsigned short* aw[2];
  const unsigned short* bw[2][3];
#pragma unroll
  for (int h = 0; h < 2; ++h) {
    int r = rs + h * 64;
    int cs = cch ^ ((r >> 1) & 3);
    aw[h] = Wb + (size_t)(row0 + r) * KTOT + cs * 8;
    int t = t0 + r;
    float dv = d[(size_t)b * TT + t];
    int dil = (int)dv; if (dil < 1) dil = 1;
    int p = t - dil; if (p < 0) p = -p; p &= (TT - 1);
    int f0 = t + dil;
    int f = (f0 >= TT) ? (TT - 1 - (f0 & (TT - 1))) : f0;
    bw[h][0] = xb + (size_t)p * CIN + cs * 8;
    bw[h][1] = xb + (size_t)t * CIN + cs * 8;
    bw[h][2] = xb + (size_t)f * CIN + cs * 8;
  }
  unsigned short* aDst[2];
  unsigned short* bDst[2];
#pragma unroll
  for (int h = 0; h < 2; ++h) {
    aDst[h] = As + h * 2048 + wid * 512;
    bDst[h] = Bs + h * 2048 + wid * 512;
  }
  int aoff[4], boff[4];
#pragma unroll
  for (int mi = 0; mi < 4; ++mi) {
    int r = wr * 64 + mi * 16 + l15;
    aoff[mi] = r * 32 + (kg ^ ((r >> 1) & 3)) * 8;
  }
#pragma unroll
  for (int ni = 0; ni < 4; ++ni) {
    int r = wc * 64 + ni * 16 + l15;
    boff[ni] = r * 32 + (kg ^ ((r >> 1) & 3)) * 8;
  }
  f32x4 acc[4][4] = {};
#pragma unroll
  for (int s = 0; s < 3; ++s) {
    for (int kt = 0; kt < 16; ++kt) {
      int koff = kt * 32;
#pragma unroll
      for (int h = 0; h < 2; ++h) {
        GLD16(aw[h] + s * CIN + koff, aDst[h]);
        GLD16(bw[h][s] + koff, bDst[h]);
      }
      __syncthreads();
      bf16x8 af[4], bf[4];
#pragma unroll
      for (int mi = 0; mi < 4; ++mi) af[mi] = *(const bf16x8*)(&As[aoff[mi]]);
#pragma unroll
      for (int ni = 0; ni < 4; ++ni) bf[ni] = *(const bf16x8*)(&Bs[boff[ni]]);
#pragma unroll
      for (int mi = 0; mi < 4; ++mi)
#pragma unroll
        for (int ni = 0; ni < 4; ++ni)
          acc[mi][ni] = MFMA(af[mi], bf[ni], acc[mi][ni]);
      __syncthreads();
    }
  }
  float* ob = out + (size_t)b * COUT * TT;
#pragma unroll
  for (int mi = 0; mi < 4; ++mi) {
    int m0 = row0 + wr * 64 + mi * 16 + kg * 4;
#pragma unroll
    for (int ni = 0; ni < 4; ++ni) {
      int t = t0 + wc * 64 + ni * 16 + l15;
#pragma unroll
      for (int j = 0; j < 4; ++j) {
        ob[(size_t)(m0 + j) * TT + t] = acc[mi][ni][j] + bias[m0 + j];
      }
    }
  }
}

extern "C" void kernel_launch(void* const* d_in, const int* in_sizes, int n_in,
                              void* d_out, int out_size, void* d_ws, size_t ws_size,
                              hipStream_t stream) {
  const float* x  = (const float*)d_in[0];
  const float* d  = (const float*)d_in[1];
  const float* W0 = (const float*)d_in[2];
  const float* b0 = (const float*)d_in[3];
  const float* W1 = (const float*)d_in[4];
  const float* W2 = (const float*)d_in[5];
  float* out = (float*)d_out;

  char* ws = (char*)d_ws;
  unsigned short* Wb  = (unsigned short*)ws;                       // 1.5 MiB
  unsigned short* xbT = (unsigned short*)(ws + (2u << 20));        // 8 MiB per batch
  const size_t SZ_XBT1 = (size_t)TT * CIN * 2;
  const size_t NEED_FULL = (size_t)(2u << 20) + (size_t)NB * SZ_XBT1;  // ~66 MiB
  const size_t NEED_MIN  = (size_t)(2u << 20) + SZ_XBT1;               // ~10 MiB

  if (ws_size >= NEED_MIN) {
    k_convert_w<<<dim3(1024, 3), 256, 0, stream>>>(W0, W1, W2, Wb);
    if (ws_size >= NEED_FULL) {
      k_transpose<<<dim3(TT / 64, CIN / 64, NB), 256, 0, stream>>>(x, xbT, 0);
      k_gemm256<<<dim3(TT / 256, COUT / 256, NB), 512, 0, stream>>>(Wb, xbT, d, b0, out);
    } else {
      for (int b = 0; b < NB; ++b) {
        k_transpose<<<dim3(TT / 64, CIN / 64, 1), 256, 0, stream>>>(x, xbT, b);
        k_gemm<<<dim3(COUT / 128, TT / 128, 1), 256, 0, stream>>>(Wb, xbT, d, b0, out, b);
      }
    }
  } else {
    // ws too small: per-batch path still needs ~10 MiB; assume harness provides it.
    for (int b = 0; b < NB; ++b) {
      k_transpose<<<dim3(TT / 64, CIN / 64, 1), 256, 0, stream>>>(x, xbT, b);
      k_gemm<<<dim3(COUT / 128, TT / 128, 1), 256, 0, stream>>>(Wb, xbT, d, b0, out, b);
    }
  }
}

// Round 4
// 144.482 us; speedup vs baseline: 1.4673x; 1.0599x over previous
//
#include <hip/hip_runtime.h>

#define TT 8192
#define CIN 512
#define COUT 512
#define NB 8
#define KTOT 1536   // 3 * CIN
#define NT 24       // K tiles of 64

typedef __attribute__((ext_vector_type(4))) float f32x4;
typedef __attribute__((ext_vector_type(8))) short bf16x8;
typedef __attribute__((ext_vector_type(8))) unsigned short u16x8;

#define GLD16(g, l) __builtin_amdgcn_global_load_lds(                      \
    (const __attribute__((address_space(1))) void*)(g),                    \
    (__attribute__((address_space(3))) void*)(l), 16, 0, 0)

#define CFENCE() asm volatile("" ::: "memory")
// compiler-level fence + hw barrier; NO sched_barrier (m141: pinning regresses)
#define SBAR() do { CFENCE(); __builtin_amdgcn_s_barrier(); CFENCE(); } while (0)
#define VMCNT4() asm volatile("s_waitcnt vmcnt(4)" ::: "memory")
#define VMCNT0() asm volatile("s_waitcnt vmcnt(0)" ::: "memory")
#define MFMA(a_, b_, c_) __builtin_amdgcn_mfma_f32_16x16x32_bf16((a_), (b_), (c_), 0, 0, 0)

__device__ inline unsigned short f2bf(float f) {
  union { float f; unsigned int u; } v; v.f = f;
  unsigned int u = v.u;
  unsigned int r = (u + 0x7FFFu + ((u >> 16) & 1u)) >> 16;  // RNE
  return (unsigned short)r;
}

__global__ void k_convert_w(const float* __restrict__ W0, const float* __restrict__ W1,
                            const float* __restrict__ W2, unsigned short* __restrict__ Wb) {
  int i = blockIdx.x * 256 + threadIdx.x;
  if (i >= COUT * CIN) return;
  const float* Ws = blockIdx.y == 0 ? W0 : (blockIdx.y == 1 ? W1 : W2);
  int o = i >> 9, c = i & 511;
  Wb[(size_t)o * KTOT + blockIdx.y * CIN + c] = f2bf(Ws[i]);
}

// x (B, C, T) fp32 -> xbT (T, C) bf16 per batch. grid (T/64, C/64, nb), block 256
__global__ void k_transpose(const float* __restrict__ x, unsigned short* __restrict__ xbT,
                            int b_base) {
  int b = b_base + blockIdx.z;
  const float* xb = x + (size_t)b * CIN * TT;
  unsigned short* xo = xbT + (size_t)blockIdx.z * TT * CIN;
  __shared__ float tile[64][65];
  int t0 = blockIdx.x * 64, c0 = blockIdx.y * 64;
  int tid = threadIdx.x;
#pragma unroll
  for (int it = 0; it < 16; ++it) {
    int L = it * 256 + tid;
    int c = L >> 6, t = L & 63;
    tile[c][t] = xb[(size_t)(c0 + c) * TT + (t0 + t)];
  }
  __syncthreads();
#pragma unroll
  for (int it = 0; it < 16; ++it) {
    int L = it * 256 + tid;
    int t = L >> 6, c = L & 63;
    xo[(size_t)(t0 + t) * CIN + (c0 + c)] = f2bf(tile[c][t]);
  }
}

// ---------------- 256x256 8-phase fused gather-GEMM ----------------
// grid (TT/256, COUT/256, NB), block 512 (8 waves, 2M x 4N)
__global__ __launch_bounds__(512) void k_gemm256(
    const unsigned short* __restrict__ Wb, const unsigned short* __restrict__ xbT,
    const float* __restrict__ d, const float* __restrict__ bias,
    float* __restrict__ out) {
  __shared__ __align__(16) unsigned short As[2][256 * 64];
  __shared__ __align__(16) unsigned short Bs[2][256 * 64];
  const int b = blockIdx.z;
  const unsigned short* xb = xbT + (size_t)b * TT * CIN;
  const int t0 = blockIdx.x * 256;
  const int row0 = blockIdx.y * 256;
  const int tid = threadIdx.x;
  const int lane = tid & 63, wid = tid >> 6;
  const int wr = wid >> 2, wc = wid & 3;
  const int l15 = lane & 15, kg = lane >> 4;

  // staging sources: round j covers row r = j*64 + (tid>>3), chunk slot tid&7
  const int srow = tid >> 3;
  const int cSrc8 = (((tid & 7) ^ ((tid >> 4) & 7))) * 8;  // swizzled 16B chunk (ushorts)
  int aOff[4];        // Wb ushort offsets, add tc*64
  int bOff[3][4];     // xbT ushort offsets per segment, add (tc&7)*64
#pragma unroll
  for (int j = 0; j < 4; ++j) {
    int r = j * 64 + srow;
    aOff[j] = (row0 + r) * KTOT + cSrc8;
    int t = t0 + r;
    float dv = d[(size_t)b * TT + t];
    int dil = (int)dv; if (dil < 1) dil = 1;
    int p = t - dil; if (p < 0) p = -p; p &= (TT - 1);
    int f0 = t + dil;
    int f = (f0 >= TT) ? (TT - 1 - (f0 & (TT - 1))) : f0;
    bOff[0][j] = p * CIN + cSrc8;
    bOff[1][j] = t * CIN + cSrc8;
    bOff[2][j] = f * CIN + cSrc8;
  }

  // fragment read offsets (swizzled): row r, chunk (kh*4+kg) ^ ((r>>1)&7)
  const int s7 = l15 >> 1;
  const int chunk0 = (kg ^ (s7 & 3)) + (s7 & 4);
  const int dK = (l15 & 8) ? -32 : 32;  // ushort delta for kh=1
  int aRd[2][4], bRd[2][2];
#pragma unroll
  for (int mh = 0; mh < 2; ++mh)
#pragma unroll
    for (int mi = 0; mi < 4; ++mi)
      aRd[mh][mi] = (wr * 128 + mh * 64 + mi * 16 + l15) * 64 + chunk0 * 8;
#pragma unroll
  for (int nh = 0; nh < 2; ++nh)
#pragma unroll
    for (int ni = 0; ni < 2; ++ni)
      bRd[nh][ni] = (wc * 64 + nh * 32 + ni * 16 + l15) * 64 + chunk0 * 8;

#define STAGE_A2(tc_, buf_, jp_) do {                                         \
    _Pragma("unroll") for (int j = 2 * (jp_); j < 2 * (jp_) + 2; ++j)         \
      GLD16(Wb + aOff[j] + (tc_) * 64, &As[buf_][j * 4096 + wid * 512]);      \
  } while (0)
#define STAGE_B2(tc_, buf_, jp_) do {                                         \
    _Pragma("unroll") for (int j = 2 * (jp_); j < 2 * (jp_) + 2; ++j)         \
      GLD16(xb + bOff[(tc_) >> 3][j] + ((tc_) & 7) * 64,                      \
            &Bs[buf_][j * 4096 + wid * 512]);                                 \
  } while (0)

  // prologue: A(0)->A[0], B(0)->B[0], B(1)->B[1]; keep B(1) in flight
  STAGE_A2(0, 0, 0); STAGE_A2(0, 0, 1);
  STAGE_B2(0, 0, 0); STAGE_B2(0, 0, 1);
  STAGE_B2(1, 1, 0); STAGE_B2(1, 1, 1);
  VMCNT4();
  SBAR();

  bf16x8 af0[4][2], af1[4][2], bfr[2][2];
  f32x4 acc[8][4] = {};

  // per tile: stage A(tc+1) at PH0/PH1 (L2-hot, short distance ok),
  //           stage B(tc+2) at PH3 (HBM-cold, ~5-phase distance).
  // tile-end vmcnt(4) keeps B(tc+2) in flight, drains A(tc+1)+B(tc+1).
#pragma unroll 2
  for (int tc = 0; tc < NT; ++tc) {
    const int cur = tc & 1;
    // ---------- PH0: read A-h0 + B-h0; stage A(tc+1) jp0; MFMA Q(0,0)
#pragma unroll
    for (int mi = 0; mi < 4; ++mi) {
      af0[mi][0] = *(const bf16x8*)&As[cur][aRd[0][mi]];
      af0[mi][1] = *(const bf16x8*)&As[cur][aRd[0][mi] + dK];
    }
#pragma unroll
    for (int ni = 0; ni < 2; ++ni) {
      bfr[ni][0] = *(const bf16x8*)&Bs[cur][bRd[0][ni]];
      bfr[ni][1] = *(const bf16x8*)&Bs[cur][bRd[0][ni] + dK];
    }
    if (tc + 1 < NT) STAGE_A2(tc + 1, cur ^ 1, 0);
    SBAR();
    __builtin_amdgcn_s_setprio(1);
#pragma unroll
    for (int mi = 0; mi < 4; ++mi)
#pragma unroll
      for (int ni = 0; ni < 2; ++ni) {
        acc[mi][ni] = MFMA(af0[mi][0], bfr[ni][0], acc[mi][ni]);
        acc[mi][ni] = MFMA(af0[mi][1], bfr[ni][1], acc[mi][ni]);
      }
    __builtin_amdgcn_s_setprio(0);
    SBAR();
    // ---------- PH1: read A-h1; stage A(tc+1) jp1; MFMA Q(1,0)
#pragma unroll
    for (int mi = 0; mi < 4; ++mi) {
      af1[mi][0] = *(const bf16x8*)&As[cur][aRd[1][mi]];
      af1[mi][1] = *(const bf16x8*)&As[cur][aRd[1][mi] + dK];
    }
    if (tc + 1 < NT) STAGE_A2(tc + 1, cur ^ 1, 1);
    SBAR();
    __builtin_amdgcn_s_setprio(1);
#pragma unroll
    for (int mi = 0; mi < 4; ++mi)
#pragma unroll
      for (int ni = 0; ni < 2; ++ni) {
        acc[4 + mi][ni] = MFMA(af1[mi][0], bfr[ni][0], acc[4 + mi][ni]);
        acc[4 + mi][ni] = MFMA(af1[mi][1], bfr[ni][1], acc[4 + mi][ni]);
      }
    __builtin_amdgcn_s_setprio(0);
    // ---------- PH2: read B-h1; barrier (publishes B[cur] fully read); MFMA Q(0,1)
#pragma unroll
    for (int ni = 0; ni < 2; ++ni) {
      bfr[ni][0] = *(const bf16x8*)&Bs[cur][bRd[1][ni]];
      bfr[ni][1] = *(const bf16x8*)&Bs[cur][bRd[1][ni] + dK];
    }
    SBAR();
    __builtin_amdgcn_s_setprio(1);
#pragma unroll
    for (int mi = 0; mi < 4; ++mi)
#pragma unroll
      for (int ni = 0; ni < 2; ++ni) {
        acc[mi][2 + ni] = MFMA(af0[mi][0], bfr[ni][0], acc[mi][2 + ni]);
        acc[mi][2 + ni] = MFMA(af0[mi][1], bfr[ni][1], acc[mi][2 + ni]);
      }
    __builtin_amdgcn_s_setprio(0);
    // ---------- PH3: stage B(tc+2) into B[cur] (safe after PH2 barrier); MFMA Q(1,1)
    if (tc + 2 < NT) { STAGE_B2(tc + 2, cur, 0); STAGE_B2(tc + 2, cur, 1); }
    __builtin_amdgcn_s_setprio(1);
#pragma unroll
    for (int mi = 0; mi < 4; ++mi)
#pragma unroll
      for (int ni = 0; ni < 2; ++ni) {
        acc[4 + mi][2 + ni] = MFMA(af1[mi][0], bfr[ni][0], acc[4 + mi][2 + ni]);
        acc[4 + mi][2 + ni] = MFMA(af1[mi][1], bfr[ni][1], acc[4 + mi][2 + ni]);
      }
    __builtin_amdgcn_s_setprio(0);
    if (tc + 2 < NT) { VMCNT4(); }        // keep B(tc+2) in flight
    else if (tc + 1 < NT) { VMCNT0(); }   // tail: drain for last tile
    SBAR();
  }

  // epilogue: bias + fp32 store
  float* ob = out + (size_t)b * COUT * TT;
#pragma unroll
  for (int mh = 0; mh < 2; ++mh)
#pragma unroll
    for (int mi = 0; mi < 4; ++mi) {
      int m0 = row0 + wr * 128 + mh * 64 + mi * 16 + kg * 4;
#pragma unroll
      for (int nh = 0; nh < 2; ++nh)
#pragma unroll
        for (int ni = 0; ni < 2; ++ni) {
          int t = t0 + wc * 64 + nh * 32 + ni * 16 + l15;
          f32x4 v = acc[mh * 4 + mi][nh * 2 + ni];
#pragma unroll
          for (int j = 0; j < 4; ++j)
            ob[(size_t)(m0 + j) * TT + t] = v[j] + bias[m0 + j];
        }
    }
}

// ---------------- fallback 128x128 (small ws) ----------------
__global__ __launch_bounds__(256) void k_gemm(
    const unsigned short* __restrict__ Wb, const unsigned short* __restrict__ xbT,
    const float* __restrict__ d, const float* __restrict__ bias,
    float* __restrict__ out, int b_base) {
  __shared__ __align__(16) unsigned short As[128 * 32];
  __shared__ __align__(16) unsigned short Bs[128 * 32];
  int b = b_base + blockIdx.z;
  const unsigned short* xb = xbT + (size_t)blockIdx.z * TT * CIN;
  int row0 = blockIdx.x * 128;
  int t0 = blockIdx.y * 128;
  int tid = threadIdx.x;
  int lane = tid & 63, wid = tid >> 6;
  int wr = wid >> 1, wc = wid & 1;
  int l15 = lane & 15, kg = lane >> 4;
  int rs = tid >> 2, cch = tid & 3;

  const unsigned short* aw[2];
  const unsigned short* bw[2][3];
#pragma unroll
  for (int h = 0; h < 2; ++h) {
    int r = rs + h * 64;
    int cs = cch ^ ((r >> 1) & 3);
    aw[h] = Wb + (size_t)(row0 + r) * KTOT + cs * 8;
    int t = t0 + r;
    float dv = d[(size_t)b * TT + t];
    int dil = (int)dv; if (dil < 1) dil = 1;
    int p = t - dil; if (p < 0) p = -p; p &= (TT - 1);
    int f0 = t + dil;
    int f = (f0 >= TT) ? (TT - 1 - (f0 & (TT - 1))) : f0;
    bw[h][0] = xb + (size_t)p * CIN + cs * 8;
    bw[h][1] = xb + (size_t)t * CIN + cs * 8;
    bw[h][2] = xb + (size_t)f * CIN + cs * 8;
  }
  unsigned short* aDst[2];
  unsigned short* bDst[2];
#pragma unroll
  for (int h = 0; h < 2; ++h) {
    aDst[h] = As + h * 2048 + wid * 512;
    bDst[h] = Bs + h * 2048 + wid * 512;
  }
  int aoff[4], boff[4];
#pragma unroll
  for (int mi = 0; mi < 4; ++mi) {
    int r = wr * 64 + mi * 16 + l15;
    aoff[mi] = r * 32 + (kg ^ ((r >> 1) & 3)) * 8;
  }
#pragma unroll
  for (int ni = 0; ni < 4; ++ni) {
    int r = wc * 64 + ni * 16 + l15;
    boff[ni] = r * 32 + (kg ^ ((r >> 1) & 3)) * 8;
  }
  f32x4 acc[4][4] = {};
#pragma unroll
  for (int s = 0; s < 3; ++s) {
    for (int kt = 0; kt < 16; ++kt) {
      int koff = kt * 32;
#pragma unroll
      for (int h = 0; h < 2; ++h) {
        GLD16(aw[h] + s * CIN + koff, aDst[h]);
        GLD16(bw[h][s] + koff, bDst[h]);
      }
      __syncthreads();
      bf16x8 af[4], bf[4];
#pragma unroll
      for (int mi = 0; mi < 4; ++mi) af[mi] = *(const bf16x8*)(&As[aoff[mi]]);
#pragma unroll
      for (int ni = 0; ni < 4; ++ni) bf[ni] = *(const bf16x8*)(&Bs[boff[ni]]);
#pragma unroll
      for (int mi = 0; mi < 4; ++mi)
#pragma unroll
        for (int ni = 0; ni < 4; ++ni)
          acc[mi][ni] = MFMA(af[mi], bf[ni], acc[mi][ni]);
      __syncthreads();
    }
  }
  float* ob = out + (size_t)b * COUT * TT;
#pragma unroll
  for (int mi = 0; mi < 4; ++mi) {
    int m0 = row0 + wr * 64 + mi * 16 + kg * 4;
#pragma unroll
    for (int ni = 0; ni < 4; ++ni) {
      int t = t0 + wc * 64 + ni * 16 + l15;
#pragma unroll
      for (int j = 0; j < 4; ++j) {
        ob[(size_t)(m0 + j) * TT + t] = acc[mi][ni][j] + bias[m0 + j];
      }
    }
  }
}

extern "C" void kernel_launch(void* const* d_in, const int* in_sizes, int n_in,
                              void* d_out, int out_size, void* d_ws, size_t ws_size,
                              hipStream_t stream) {
  const float* x  = (const float*)d_in[0];
  const float* d  = (const float*)d_in[1];
  const float* W0 = (const float*)d_in[2];
  const float* b0 = (const float*)d_in[3];
  const float* W1 = (const float*)d_in[4];
  const float* W2 = (const float*)d_in[5];
  float* out = (float*)d_out;

  char* ws = (char*)d_ws;
  unsigned short* Wb  = (unsigned short*)ws;                       // 1.5 MiB
  unsigned short* xbT = (unsigned short*)(ws + (2u << 20));        // 8 MiB per batch
  const size_t SZ_XBT1 = (size_t)TT * CIN * 2;
  const size_t NEED_FULL = (size_t)(2u << 20) + (size_t)NB * SZ_XBT1;  // ~66 MiB
  const size_t NEED_MIN  = (size_t)(2u << 20) + SZ_XBT1;               // ~10 MiB

  if (ws_size >= NEED_MIN) {
    k_convert_w<<<dim3(1024, 3), 256, 0, stream>>>(W0, W1, W2, Wb);
    if (ws_size >= NEED_FULL) {
      k_transpose<<<dim3(TT / 64, CIN / 64, NB), 256, 0, stream>>>(x, xbT, 0);
      k_gemm256<<<dim3(TT / 256, COUT / 256, NB), 512, 0, stream>>>(Wb, xbT, d, b0, out);
    } else {
      for (int b = 0; b < NB; ++b) {
        k_transpose<<<dim3(TT / 64, CIN / 64, 1), 256, 0, stream>>>(x, xbT, b);
        k_gemm<<<dim3(COUT / 128, TT / 128, 1), 256, 0, stream>>>(Wb, xbT, d, b0, out, b);
      }
    }
  } else {
    for (int b = 0; b < NB; ++b) {
      k_transpose<<<dim3(TT / 64, CIN / 64, 1), 256, 0, stream>>>(x, xbT, b);
      k_gemm<<<dim3(COUT / 128, TT / 128, 1), 256, 0, stream>>>(Wb, xbT, d, b0, out, b);
    }
  }
}